// Round 4
// baseline (1040.071 us; speedup 1.0000x reference)
//
#include <hip/hip_runtime.h>

typedef _Float16 f16x8 __attribute__((ext_vector_type(8)));
typedef float f32x4 __attribute__((ext_vector_type(4)));

#define Dd  256
#define Hh  1024
#define BM  4            // batch rows per block (replicated 4x across MFMA quads)
#define ZSTR (Dd + 8)
#define ASTR (Hh + 8)

// ---------------- prep: transpose + cast fp32 -> fp16 ----------------
__global__ void transpose_cast_kernel(const float* __restrict__ src,
                                      _Float16* __restrict__ dst,
                                      int R, int C) {
    __shared__ float tile[32][33];
    const int bx = blockIdx.x * 32;
    const int by = blockIdx.y * 32;
    const int x = threadIdx.x;
    const int y0 = threadIdx.y;
#pragma unroll
    for (int i = 0; i < 4; ++i) {
        int y = y0 + i * 8;
        tile[y][x] = src[(by + y) * C + bx + x];
    }
    __syncthreads();
#pragma unroll
    for (int i = 0; i < 4; ++i) {
        int y = y0 + i * 8;
        dst[(bx + y) * R + by + x] = (_Float16)tile[x][y];
    }
}

// ---------------- main: zero-sync, full-chip TLP ----------------
// 256 blocks x 512 threads (8 waves) = 2048 waves on 256 CUs. Block owns 4
// batch rows for the whole solve; rows are replicated across the 4 MFMA row-
// quads (C row q*4+r holds batch row r in every quad q) — trades 4x MFMA
// waste (MfmaUtil was 1.5%, irrelevant) for 4x thread-level parallelism on
// the latency-bound weight stream. All 32 blocks per XCD read the SAME 1 MB
// of weights -> L2-resident. Zero inter-block communication.
__global__ __launch_bounds__(512, 2) void ode_kernel(
    const float* __restrict__ z0, const float* __restrict__ tv,
    const float* __restrict__ b1, const float* __restrict__ b2,
    const _Float16* __restrict__ W1T,   // [Hh][Dd] fp16 (W1 transposed)
    const _Float16* __restrict__ W2T,   // [Dd][Hh] fp16 (W2 transposed)
    float* __restrict__ out) {
    __shared__ _Float16 z_lds[16][ZSTR];     // rows m: batch m0+(m&3), quad-replicated
    __shared__ _Float16 act_lds[16][ASTR];   // same replication

    const int tid  = threadIdx.x;
    const int w    = tid >> 6;
    const int lane = tid & 63;
    const int ln   = lane & 15;
    const int q    = lane >> 4;
    const int m0   = blockIdx.x * BM;

    const float h = (tv[1] - tv[0]) * 0.125f;

    float bb1[8];
#pragma unroll
    for (int nt = 0; nt < 8; ++nt) bb1[nt] = b1[w * 128 + nt * 16 + ln];
    float bb2v[2];
#pragma unroll
    for (int t = 0; t < 2; ++t) bb2v[t] = b2[w * 32 + t * 16 + ln];

    // per-wave weight fragment base pointers
    const _Float16* W1b = W1T + (w * 128 + ln) * Dd + q * 8;  // + nt*16*Dd + kk*32
    const _Float16* W2b = W2T + (w * 32 + ln) * Hh + q * 8;   // + t*16*Hh + kk*32

    // RK4 state (replicated across quads): z[t][r] = z[m0+r][w*32+t*16+ln]
    f32x4 z[2], zsum[2];
#pragma unroll
    for (int t = 0; t < 2; ++t)
#pragma unroll
        for (int r = 0; r < 4; ++r)
            z[t][r] = z0[(m0 + r) * Dd + w * 32 + t * 16 + ln];
#pragma unroll
    for (int t = 0; t < 2; ++t)
#pragma unroll
        for (int r = 0; r < 4; ++r)
            z_lds[q * 4 + r][w * 32 + t * 16 + ln] = (_Float16)z[t][r];
    __syncthreads();

#pragma unroll 1
    for (int ev = 0; ev < 32; ++ev) {
        const int e = ev & 3;

        // ---- GEMM1: act[:, w*128..+128) = tanh(z_arg @ W1 + b1) ----
        f16x8 a1[8];
#pragma unroll
        for (int kk = 0; kk < 8; ++kk)
            a1[kk] = *(const f16x8*)&z_lds[ln][kk * 32 + q * 8];

#pragma unroll
        for (int nt = 0; nt < 8; ++nt) {
            f32x4 acc = {0.f, 0.f, 0.f, 0.f};
#pragma unroll
            for (int kk = 0; kk < 8; ++kk)
                acc = __builtin_amdgcn_mfma_f32_16x16x32_f16(
                        a1[kk], *(const f16x8*)&W1b[(nt * 16) * Dd + kk * 32],
                        acc, 0, 0, 0);
#pragma unroll
            for (int r = 0; r < 4; ++r) {
                float x = acc[r] + bb1[nt];
                float ex = __expf(2.0f * x);
                act_lds[q * 4 + r][w * 128 + nt * 16 + ln] =
                    (_Float16)(1.0f - 2.0f / (ex + 1.0f));
            }
        }
        __syncthreads();

        // ---- GEMM2: k[:, w*32..+32) = act @ W2 + b2 ----
        f32x4 acc2[2] = {{0.f, 0.f, 0.f, 0.f}, {0.f, 0.f, 0.f, 0.f}};
#pragma unroll
        for (int kk = 0; kk < 32; ++kk) {
            f16x8 a2 = *(const f16x8*)&act_lds[ln][kk * 32 + q * 8];
#pragma unroll
            for (int t = 0; t < 2; ++t)
                acc2[t] = __builtin_amdgcn_mfma_f32_16x16x32_f16(
                            a2, *(const f16x8*)&W2b[(t * 16) * Hh + kk * 32],
                            acc2[t], 0, 0, 0);
        }

        // ---- RK4 epilogue (registers, quad-replicated) ----
#pragma unroll
        for (int t = 0; t < 2; ++t) {
            f32x4 kv, za;
#pragma unroll
            for (int r = 0; r < 4; ++r) kv[r] = acc2[t][r] + bb2v[t];
            if (e == 0) {
                zsum[t] = kv;
            } else if (e == 3) {
#pragma unroll
                for (int r = 0; r < 4; ++r) zsum[t][r] += kv[r];
            } else {
#pragma unroll
                for (int r = 0; r < 4; ++r) zsum[t][r] += 2.0f * kv[r];
            }
            if (e < 3) {
                const float c = (e == 2) ? h : 0.5f * h;
#pragma unroll
                for (int r = 0; r < 4; ++r) za[r] = z[t][r] + c * kv[r];
            } else {
#pragma unroll
                for (int r = 0; r < 4; ++r) {
                    z[t][r] += (h * (1.0f / 6.0f)) * zsum[t][r];
                    za[r] = z[t][r];
                }
            }
#pragma unroll
            for (int r = 0; r < 4; ++r)
                z_lds[q * 4 + r][w * 32 + t * 16 + ln] = (_Float16)za[r];
        }
        __syncthreads();
    }

    // final state -> out (quad 0 writes; all quads hold identical copies)
    if (q == 0) {
#pragma unroll
        for (int t = 0; t < 2; ++t)
#pragma unroll
            for (int r = 0; r < 4; ++r)
                out[(m0 + r) * Dd + w * 32 + t * 16 + ln] = z[t][r];
    }
}

extern "C" void kernel_launch(void* const* d_in, const int* in_sizes, int n_in,
                              void* d_out, int out_size, void* d_ws, size_t ws_size,
                              hipStream_t stream) {
    const float* z0 = (const float*)d_in[0];
    const float* tv = (const float*)d_in[1];
    const float* W1 = (const float*)d_in[2];   // [256][1024]
    const float* b1 = (const float*)d_in[3];   // [1024]
    const float* W2 = (const float*)d_in[4];   // [1024][256]
    const float* b2 = (const float*)d_in[5];   // [256]
    float* out = (float*)d_out;

    _Float16* W1T = (_Float16*)d_ws;           // [1024][256] fp16, 512 KB
    _Float16* W2T = W1T + Hh * Dd;             // [256][1024] fp16, 512 KB

    dim3 blk(32, 8);
    transpose_cast_kernel<<<dim3(Hh / 32, Dd / 32), blk, 0, stream>>>(W1, W1T, Dd, Hh);
    transpose_cast_kernel<<<dim3(Dd / 32, Hh / 32), blk, 0, stream>>>(W2, W2T, Hh, Dd);

    ode_kernel<<<256, 512, 0, stream>>>(z0, tv, b1, b2, W1T, W2T, out);
}